// Round 1
// baseline (421.253 us; speedup 1.0000x reference)
//
#include <hip/hip_runtime.h>

// Reference = patchify ∘ depatchify = identity. Pure D2D copy.
// 64*1*1024*1024 floats = 256 MiB; float4 grid-stride copy targets ~6.3 TB/s.

__global__ __launch_bounds__(256) void copy_f4(const float4* __restrict__ src,
                                               float4* __restrict__ dst,
                                               long long n4) {
    long long i = (long long)blockIdx.x * blockDim.x + threadIdx.x;
    long long stride = (long long)gridDim.x * blockDim.x;
    for (; i < n4; i += stride) {
        dst[i] = src[i];
    }
}

extern "C" void kernel_launch(void* const* d_in, const int* in_sizes, int n_in,
                              void* d_out, int out_size, void* d_ws, size_t ws_size,
                              hipStream_t stream) {
    const float* images = (const float*)d_in[0];
    float* out = (float*)d_out;

    long long n = (long long)out_size;          // 67,108,864 floats
    long long n4 = n / 4;                        // divisible (h*w = 1M)

    // Enough blocks to saturate 256 CUs with several waves each, but bounded.
    int block = 256;
    long long want = (n4 + block - 1) / block;
    int grid = (int)(want > 32768 ? 32768 : want);

    copy_f4<<<grid, block, 0, stream>>>((const float4*)images, (float4*)out, n4);
}